// Round 12
// baseline (262.000 us; speedup 1.0000x reference)
//
#include <hip/hip_runtime.h>

// GCN: h1 = relu( Din^-1/2 * A * Dout^-1/2 * (X W1) + b1 )
//      h2 =       Din^-1/2 * A * Dout^-1/2 * (h1 W2) + b2
//      out = mean_nodes(h2)                         [128]
// R12 structure:
//  - mega2 reverted to R9 schedule (1166 blocks, per-tile GEMM, VGPR 76):
//    R11's exact-768 1-round grid removed scheduler refill -> idle slots
//    (66us, occ 14.5%). Oversubscribe heterogeneous-role grids.
//    Gated wsum gather kept (normIn[dst] only for filter-passing edges).
//  - spmm restructured PASS-OUTER over 4 src-quarters: each quarter of H
//    is 3.2MB < 4MB per-XCD L2. Wave keeps 8 nodes' acc/col-rows in
//    registers (static-indexed), scans index lists 4x with wave-uniform
//    quarter filter (readlane broadcast -> s_cbranch, no divergence).
//    Tests whether spmm's ~3.6TB/s is an L3 random-read ceiling (fix:
//    L2-localized windows) vs a flat random-transaction pipe (then spmm
//    is at floor).
// Laws: device atomics ~flat 13-20K/us (poison); ~8-9us per dispatch
// boundary; cross-XCD sw-fences unsafe (R7/R10); scheduler refill needed.

#define NNODES 50000
#define NEDGES 800000
#define CH      64                       // edge chunks
#define EPC     (NEDGES / CH)            // 12500 edges per chunk
#define NVEC    12                       // 12*1024 = 12288 edges vectorized
#define TAILB   (NVEC * 1024)            // 12288
#define TAILN   (EPC - TAILB)            // 212 scalar-tail edges
#define HWORDS  12500                    // u32 words per node-half (2 nodes/word)
#define QN      12500                    // wsum quarter width
#define G1_BM   ((NNODES + 127) / 128)   // 391
#define MEGA_NB (128 + 256 + 2 * G1_BM)  // 1166 (R9 schedule, refillable)
#define WS_NB   1563                     // spmm grid: ceil(12500/8) -> <=8 qds/block
#define NQUAD   (NNODES / 4)             // 12500
#define NPASS   4
#define PQ      12500                    // src-quarter width (3.2MB of H)

typedef __bf16 bf16x8 __attribute__((ext_vector_type(8)));
typedef float f32x4 __attribute__((ext_vector_type(4)));
typedef float f32x2 __attribute__((ext_vector_type(2)));

__device__ __forceinline__ unsigned short f2b(float f) {
    union { float f; unsigned u; } v; v.f = f;
    unsigned r = 0x7fffu + ((v.u >> 16) & 1u);
    return (unsigned short)((v.u + r) >> 16);
}
__device__ __forceinline__ unsigned char f2fp8(float x) {
    return (unsigned char)(__builtin_amdgcn_cvt_pk_fp8_f32(x, x, 0, false) & 0xff);
}
__device__ __forceinline__ float rdeg(int d) {      // rsqrt(max(d,1))
    return __frsqrt_rn((float)max(d, 1));
}

// ---------------- hist0: W1 cast + dst-hist (degIn) + src-hist (degOut) ----------------
__global__ __launch_bounds__(256) void k_hist0(
    const float* __restrict__ W1, unsigned short* __restrict__ W1t,
    const int* __restrict__ src, const int* __restrict__ dst,
    unsigned* __restrict__ degInP,   // [128][HWORDS]
    unsigned* __restrict__ degOutP)  // [128][HWORDS]
{
    __shared__ unsigned lds[HWORDS];   // 50 KB
    int bid = blockIdx.x, tid = threadIdx.x;

    if (bid < 256) {
        int id = bid * 256 + tid;      // 65536
        int k = id >> 8, n = id & 255;
        W1t[n * 256 + k] = f2b(W1[id]);
        return;
    }

    int b = bid - 256;                  // [0,256)
    const int* key = (b < 128) ? dst : src;
    unsigned* outP = (b < 128) ? degInP : degOutP;
    int b2 = b & 127;
    int c = b2 >> 1, h = b2 & 1;
    int lo = h * 25000;

    for (int i = tid; i < HWORDS; i += 256) lds[i] = 0;
    __syncthreads();
    int base = c * EPC;
    for (int i = 0; i < NVEC; i++) {
        int e = base + (i * 256 + tid) * 4;
        int4 k4 = *(const int4*)&key[e];
        int kk[4] = {k4.x, k4.y, k4.z, k4.w};
#pragma unroll
        for (int u = 0; u < 4; u++) {
            unsigned r = (unsigned)(kk[u] - lo);
            if (r < 25000u) atomicAdd(&lds[r >> 1], 1u << ((r & 1) * 16));
        }
    }
    if (tid < TAILN) {
        unsigned r = (unsigned)(key[base + TAILB + tid] - lo);
        if (r < 25000u) atomicAdd(&lds[r >> 1], 1u << ((r & 1) * 16));
    }
    __syncthreads();
    unsigned* op = outP + (size_t)b2 * HWORDS;
    for (int i = tid; i < HWORDS; i += 256) op[i] = lds[i];
}

// ---------------- merge0: prefix degInP -> chunkStart; degIn/degOut -> norms ----------------
__global__ __launch_bounds__(256) void k_merge0(
    const unsigned* __restrict__ degInP, const unsigned* __restrict__ degOutP,
    unsigned* __restrict__ chunkStartPk,   // [128][HWORDS]
    float* __restrict__ normIn, float* __restrict__ normOut,
    int* __restrict__ degc)
{
    int id = blockIdx.x * blockDim.x + threadIdx.x;
    if (id >= 25000) return;
    int h = id >= HWORDS, w = id - h * HWORDS;
    unsigned runLo = 0, runHi = 0, oLo = 0, oHi = 0;
#pragma unroll 8
    for (int c = 0; c < CH; c++) {
        size_t idx = (size_t)(c * 2 + h) * HWORDS + w;
        unsigned x = degInP[idx];
        chunkStartPk[idx] = runLo | (runHi << 16);
        runLo += x & 0xffffu; runHi += x >> 16;
        unsigned y = degOutP[idx];
        oLo += y & 0xffffu; oHi += y >> 16;
    }
    int d0 = h * 25000 + 2 * w, d1 = d0 + 1;
    normIn[d0] = rdeg((int)runLo);  normIn[d1] = rdeg((int)runHi);
    normOut[d0] = rdeg((int)oLo);   normOut[d1] = rdeg((int)oHi);
    degc[d0] = min((int)runLo, 64); degc[d1] = min((int)runHi, 64);
}

// ---------------- MEGA-2: edge-scatter + wsum-hist + GEMM1 (R9 refillable schedule) ----------------
__global__ __launch_bounds__(256) void k_mega2(
    const int* __restrict__ src, const int* __restrict__ dst,
    const unsigned* __restrict__ chunkStartPk,
    unsigned short* __restrict__ col2,
    const float* __restrict__ normIn, const float* __restrict__ normOut,
    float* __restrict__ wsumP,
    const float* __restrict__ X, const unsigned short* __restrict__ W1t,
    unsigned char* __restrict__ H, int M)
{
    __shared__ __align__(16) unsigned char smem[50048];   // 50KB union
    int bid = blockIdx.x, tid = threadIdx.x;

    if (bid < 128) {
        // ---- counting-sort scatter (int4 edges) ----
        unsigned* cntL = (unsigned*)smem;
        int c = bid >> 1, h = bid & 1;
        int lo = h * 25000;
        const unsigned* cs = chunkStartPk + (size_t)(c * 2 + h) * HWORDS;
        for (int i = tid; i < HWORDS; i += 256) cntL[i] = cs[i];
        __syncthreads();
        int base = c * EPC;
        for (int i = 0; i < NVEC; i++) {
            int e = base + (i * 256 + tid) * 4;
            int4 d4 = *(const int4*)&dst[e];
            int4 s4 = *(const int4*)&src[e];
            int dd[4] = {d4.x, d4.y, d4.z, d4.w};
            int ss[4] = {s4.x, s4.y, s4.z, s4.w};
#pragma unroll
            for (int u = 0; u < 4; u++) {
                unsigned r = (unsigned)(dd[u] - lo);
                if (r < 25000u) {
                    unsigned sh = (r & 1) * 16;
                    unsigned wv = atomicAdd(&cntL[r >> 1], 1u << sh);
                    unsigned slot = (wv >> sh) & 0xffffu;
                    if (slot < 64) col2[(size_t)dd[u] * 64 + slot] = (unsigned short)ss[u];
                }
            }
        }
        if (tid < TAILN) {
            int e = base + TAILB + tid;
            int d = dst[e];
            unsigned r = (unsigned)(d - lo);
            if (r < 25000u) {
                int s = src[e];
                unsigned sh = (r & 1) * 16;
                unsigned wv = atomicAdd(&cntL[r >> 1], 1u << sh);
                unsigned slot = (wv >> sh) & 0xffffu;
                if (slot < 64) col2[(size_t)d * 64 + slot] = (unsigned short)s;
            }
        }
        return;
    }

    if (bid < 384) {
        // ---- wsum-hist role: gated normIn gather ----
        float* wf = (float*)smem;
        int b2 = bid - 128;            // [0,256)
        int c = b2 >> 2, q = b2 & 3;
        int lo = q * QN;
        for (int i = tid; i < QN; i += 256) wf[i] = 0.f;
        __syncthreads();
        int base = c * EPC;
        for (int i = 0; i < NVEC; i++) {
            int e = base + (i * 256 + tid) * 4;
            int4 s4 = *(const int4*)&src[e];
            int4 d4 = *(const int4*)&dst[e];
            int ss[4] = {s4.x, s4.y, s4.z, s4.w};
            int dd[4] = {d4.x, d4.y, d4.z, d4.w};
#pragma unroll
            for (int u = 0; u < 4; u++) {
                unsigned r = (unsigned)(ss[u] - lo);
                if (r < (unsigned)QN) {
                    float ni = normIn[dd[u]];
                    atomicAdd(&wf[r], ni);
                }
            }
        }
        if (tid < TAILN) {
            int e = base + TAILB + tid;
            unsigned r = (unsigned)(src[e] - lo);
            if (r < (unsigned)QN) atomicAdd(&wf[r], normIn[dst[e]]);
        }
        __syncthreads();
        float* op = wsumP + (size_t)b2 * QN;
        for (int i = tid; i < QN; i += 256) op[i] = wf[i];
        return;
    }

    // ---- GEMM1 role: one 128x128 tile per block (refillable) ----
    unsigned short (*As)[40] = (unsigned short (*)[40])smem;
    unsigned short (*Bs)[40] = (unsigned short (*)[40])(smem + 10240);
    int g = bid - 384;                  // [0, 782)
    int bm = g % G1_BM, bn = g / G1_BM;
    int m0 = bm * 128, n0 = bn * 128;
    int lane = tid & 63, wave = tid >> 6;
    int wm = (wave >> 1) * 64, wn = (wave & 1) * 64;
    int q = lane >> 4, r16 = lane & 15;

    f32x4 acc[4][4];
#pragma unroll
    for (int i = 0; i < 4; i++)
#pragma unroll
        for (int j = 0; j < 4; j++) acc[i][j] = 0.f;

    int c0 = tid, c1 = tid + 256;
    int r0 = c0 >> 2, k0c = (c0 & 3) * 8;
    int r1 = c1 >> 2, k1c = (c1 & 3) * 8;
    const float* Ar0 = X + (size_t)min(m0 + r0, M - 1) * 256;
    const float* Ar1 = X + (size_t)min(m0 + r1, M - 1) * 256;
    const unsigned short* Br0 = W1t + (size_t)(n0 + r0) * 256;
    const unsigned short* Br1 = W1t + (size_t)(n0 + r1) * 256;

    auto pk2u = [](float a, float b) -> unsigned {
        unsigned short x = f2b(a), y = f2b(b);
        return (unsigned)x | ((unsigned)y << 16);
    };

    for (int k0 = 0; k0 < 256; k0 += 32) {
        float4 fa0 = *(const float4*)(Ar0 + k0 + k0c);
        float4 fa1 = *(const float4*)(Ar0 + k0 + k0c + 4);
        float4 fb0 = *(const float4*)(Ar1 + k0 + k1c);
        float4 fb1 = *(const float4*)(Ar1 + k0 + k1c + 4);
        uint4 vb0 = *(const uint4*)(Br0 + k0 + k0c);
        uint4 vb1 = *(const uint4*)(Br1 + k0 + k1c);
        uint4 va0 = make_uint4(pk2u(fa0.x, fa0.y), pk2u(fa0.z, fa0.w), pk2u(fa1.x, fa1.y), pk2u(fa1.z, fa1.w));
        uint4 va1 = make_uint4(pk2u(fb0.x, fb0.y), pk2u(fb0.z, fb0.w), pk2u(fb1.x, fb1.y), pk2u(fb1.z, fb1.w));
        __syncthreads();
        *(uint4*)&As[r0][k0c] = va0;
        *(uint4*)&As[r1][k1c] = va1;
        *(uint4*)&Bs[r0][k0c] = vb0;
        *(uint4*)&Bs[r1][k1c] = vb1;
        __syncthreads();
        bf16x8 af[4], bf[4];
#pragma unroll
        for (int i = 0; i < 4; i++)
            af[i] = *(const bf16x8*)&As[wm + i * 16 + r16][q * 8];
#pragma unroll
        for (int j = 0; j < 4; j++)
            bf[j] = *(const bf16x8*)&Bs[wn + j * 16 + r16][q * 8];
#pragma unroll
        for (int i = 0; i < 4; i++)
#pragma unroll
            for (int j = 0; j < 4; j++)
                acc[i][j] = __builtin_amdgcn_mfma_f32_16x16x32_bf16(af[i], bf[j], acc[i][j], 0, 0, 0);
    }

#pragma unroll
    for (int i = 0; i < 4; i++) {
#pragma unroll
        for (int rr = 0; rr < 4; rr++) {
            int m = m0 + wm + i * 16 + q * 4 + rr;
            if (m < M) {
                float no = normOut[m];
                unsigned char* Hp = H + (size_t)m * 256 + n0 + wn + r16;
#pragma unroll
                for (int j = 0; j < 4; j++)
                    Hp[j * 16] = f2fp8(acc[i][j][rr] * no);
            }
        }
    }
}

// ---------------- merge1: wsum partials -> meta = {wgt, normIn, degc, 0} ----------------
__global__ __launch_bounds__(256) void k_merge1(
    const float* __restrict__ wsumP, const float* __restrict__ normOut,
    const float* __restrict__ normIn, const int* __restrict__ degc,
    float4* __restrict__ meta)
{
    int i = blockIdx.x * blockDim.x + threadIdx.x;
    if (i >= NNODES) return;
    int q = i / QN, li = i - q * QN;
    float ws = 0.f;
#pragma unroll 8
    for (int c = 0; c < CH; c++) ws += wsumP[(size_t)(c * 4 + q) * QN + li];
    meta[i] = make_float4(normOut[i] * ws, normIn[i],
                          __int_as_float(degc[i]), 0.f);
}

// ---------------- SpMM layer1: PASS-OUTER quarter-localized gathers ----------------
// Each wave holds 8 nodes' state in registers (static-indexed). 4 passes;
// pass p gathers only H rows in [p*12500,(p+1)*12500) = 3.2MB (fits XCD L2).
// Quarter filter is wave-uniform (readlane broadcast) -> no divergence.
__global__ __launch_bounds__(256) void k_spmm_wsum(
    const unsigned char* __restrict__ H, const float4* __restrict__ meta,
    const int* __restrict__ degc, const unsigned short* __restrict__ col2,
    const float* __restrict__ bias, float* __restrict__ vpart) {
    __shared__ float sm[4][256];
    int wave = threadIdx.x >> 6;
    int lane = threadIdx.x & 63;
    int f = lane * 4;
    const unsigned char* Hf = H + f;
    int bid = blockIdx.x;

    // prologue: load up to 8 nodes' col rows + clamped degrees; zero acc
    int colr[8];
    int di[8];
    float a[8][4];
#pragma unroll
    for (int qi = 0; qi < 8; qi++) {
        int qd = bid + qi * WS_NB;
        colr[qi] = 0; di[qi] = 0;
        a[qi][0] = a[qi][1] = a[qi][2] = a[qi][3] = 0.f;
        if (qd < NQUAD) {
            int node = qd * 4 + wave;
            di[qi] = degc[node];
            colr[qi] = (int)col2[(size_t)node * 64 + lane];
        }
    }

    // pass-outer gather
    for (int p = 0; p < NPASS; p++) {
        int plo = p * PQ;
#pragma unroll
        for (int qi = 0; qi < 8; qi++) {
            int dI = di[qi];
            int myc = colr[qi];
            for (int i = 0; i < dI; i += 16) {
#pragma unroll
                for (int u = 0; u < 16; u++) {
                    if (i + u < dI) {
                        int c = __builtin_amdgcn_readlane(myc, i + u);
                        if ((unsigned)(c - plo) < (unsigned)PQ) {
                            unsigned v = *(const unsigned*)(Hf + (size_t)c * 256);
                            f32x2 l2 = __builtin_amdgcn_cvt_pk_f32_fp8(v, false);
                            f32x2 h2 = __builtin_amdgcn_cvt_pk_f32_fp8(v, true);
                            a[qi][0] += l2.x; a[qi][1] += l2.y;
                            a[qi][2] += h2.x; a[qi][3] += h2.y;
                        }
                    }
                }
            }
        }
    }

    // finalize: relu + weighted sum over my nodes
    float4 bv = *(const float4*)(bias + f);
    float vac0 = 0.f, vac1 = 0.f, vac2 = 0.f, vac3 = 0.f;
#pragma unroll
    for (int qi = 0; qi < 8; qi++) {
        int qd = bid + qi * WS_NB;
        if (qd < NQUAD) {
            int node = qd * 4 + wave;
            float4 pM = meta[node];
            float wn = pM.x, nI = pM.y;
            vac0 += wn * fmaxf(a[qi][0] * nI + bv.x, 0.f);
            vac1 += wn * fmaxf(a[qi][1] * nI + bv.y, 0.f);
            vac2 += wn * fmaxf(a[qi][2] * nI + bv.z, 0.f);
            vac3 += wn * fmaxf(a[qi][3] * nI + bv.w, 0.f);
        }
    }

    *(float4*)&sm[wave][f] = make_float4(vac0, vac1, vac2, vac3);
    __syncthreads();
    int t = threadIdx.x;
    float s4 = sm[0][t] + sm[1][t] + sm[2][t] + sm[3][t];
    vpart[(size_t)bid * 256 + t] = s4;
}

// ---------------- tree reduce stage: WS_NB rows -> 64 rows ----------------
__global__ __launch_bounds__(256) void k_red1(const float* __restrict__ vpart,
                                              float* __restrict__ vred) {
    int b = blockIdx.x;
    int t = threadIdx.x;
    float s = 0.f;
    for (int i = b; i < WS_NB; i += 64) s += vpart[(size_t)i * 256 + t];
    vred[(size_t)b * 256 + t] = s;
}

// ---------------- final: v = sum(vred); out = v@W2/N + b2 ----------------
__global__ __launch_bounds__(1024) void k_final(
    const float* __restrict__ vred, const float* __restrict__ W2,
    const float* __restrict__ b2, float* __restrict__ out) {
    __shared__ float part[4][256];
    __shared__ float v[256];
    int t = threadIdx.x;
    int feat = t & 255, pr = t >> 8;
    float s = 0.f;
    for (int i = pr; i < 64; i += 4) s += vred[(size_t)i * 256 + feat];
    part[pr][feat] = s;
    __syncthreads();
    if (t < 256) v[t] = part[0][t] + part[1][t] + part[2][t] + part[3][t];
    __syncthreads();
    if (t < 128) {
        float o = 0.f;
        for (int k = 0; k < 256; k++) o += v[k] * W2[k * 128 + t];
        out[t] = o * (1.0f / (float)NNODES) + b2[t];
    }
}

extern "C" void kernel_launch(void* const* d_in, const int* in_sizes, int n_in,
                              void* d_out, int out_size, void* d_ws, size_t ws_size,
                              hipStream_t stream) {
    const float* X   = (const float*)d_in[0];
    const int*   src = (const int*)d_in[1];
    const int*   dst = (const int*)d_in[2];
    const float* W1  = (const float*)d_in[3];
    const float* b1  = (const float*)d_in[4];
    const float* W2  = (const float*)d_in[5];
    const float* b2  = (const float*)d_in[6];
    float* out = (float*)d_out;

    const int n = NNODES;

    char* p = (char*)d_ws;
    auto carve = [&](size_t bytes) -> void* {
        void* r = (void*)p;
        p += (bytes + 255) & ~(size_t)255;
        return r;
    };
    unsigned short* col2 = (unsigned short*)carve((size_t)n * 64 * 2);      // 6.4 MB
    unsigned short* W1t  = (unsigned short*)carve((size_t)256 * 256 * 2);
    unsigned char*  bufA = (unsigned char*)carve((size_t)n * 256);          // 12.8 MB fp8 H'
    float* normIn  = (float*)carve((size_t)n * sizeof(float));
    float* normOut = (float*)carve((size_t)n * sizeof(float));
    int*   degc    = (int*)carve((size_t)n * sizeof(int));
    float4* meta   = (float4*)carve((size_t)n * sizeof(float4));            // 800 KB
    // degInP/degOutP dead after merge0 -> region reused by wsumP (born in mega2)
    size_t histP_bytes = (size_t)128 * HWORDS * sizeof(unsigned);           // 6.4 MB each
    char* histr = (char*)carve(2 * histP_bytes);                            // 12.8 MB
    unsigned* degInP  = (unsigned*)histr;
    unsigned* degOutP = (unsigned*)(histr + histP_bytes);
    float*    wsumP   = (float*)histr;                                      // [256][QN] alias
    // chunkStartPk dead after mega2 -> region reused by vpart/vred
    char* csr = (char*)carve(histP_bytes);                                  // 6.4 MB
    unsigned* chunkStartPk = (unsigned*)csr;
    float* vpart = (float*)csr;                                             // 1.6 MB alias
    float* vred  = (float*)(csr + (size_t)WS_NB * 256 * sizeof(float));

    // ---- hist0: W1 cast + dst/src LDS histograms ----
    k_hist0<<<512, 256, 0, stream>>>(W1, W1t, src, dst, degInP, degOutP);

    // ---- merge0: prefix -> chunkStart, norms, degc ----
    k_merge0<<<98, 256, 0, stream>>>(degInP, degOutP, chunkStartPk,
                                     normIn, normOut, degc);

    // ---- MEGA-2: scatter || wsum (gated) || GEMM1 -- R9 refillable grid ----
    k_mega2<<<MEGA_NB, 256, 0, stream>>>(
        src, dst, chunkStartPk, col2, normIn, normOut, wsumP, X, W1t, bufA, n);

    // ---- merge1: meta = {wgt, normIn, degc} ----
    k_merge1<<<(n + 255) / 256, 256, 0, stream>>>(wsumP, normOut, normIn, degc, meta);

    // ---- layer-1 gather: pass-outer quarter-localized spmm ----
    k_spmm_wsum<<<WS_NB, 256, 0, stream>>>(bufA, meta, degc, col2, b1, vpart);

    // ---- tree reduce + final matvec ----
    k_red1<<<64, 256, 0, stream>>>(vpart, vred);
    k_final<<<1, 1024, 0, stream>>>(vred, W2, b2, out);
}

// Round 13
// 202.656 us; speedup vs baseline: 1.2928x; 1.2928x over previous
//
#include <hip/hip_runtime.h>

// GCN: h1 = relu( Din^-1/2 * A * Dout^-1/2 * (X W1) + b1 )
//      h2 =       Din^-1/2 * A * Dout^-1/2 * (h1 W2) + b2
//      out = mean_nodes(h2)                         [128]
// R13 = union of proven-best pieces (R9 + gated wsum):
//   - spmm: R9's exact unconditional 16-wide gather batches (R12's
//     per-gather predicates serialized loads: 57->101us. Any conditional
//     around a gather forfeits the in-flight batch).
//   - mega2: R9's refillable 1166-block schedule + R12's gated wsum
//     gather (normIn[dst] only for filter-passing edges).
// MEASURED LAWS (final set):
//   * device random transactions (scatter/gather/atomic RMW) retire at
//     ~14-16K wave-ops/us device-wide, address-layout-independent;
//     atomics ~2x cost. mega2 (800K scatters) and spmm (900K gathers)
//     both sit AT this floor.
//   * ~8-9us per dispatch boundary; cross-XCD sw-fences/grid.sync are
//     unsafe on this harness (R7, R10) -> 7-dispatch structure is fixed.
//   * gather batches must be unconditional to stay in flight (R12).
//   * oversubscribe heterogeneous-role grids for scheduler refill (R11).

#define NNODES 50000
#define NEDGES 800000
#define CH      64                       // edge chunks
#define EPC     (NEDGES / CH)            // 12500 edges per chunk
#define NVEC    12                       // 12*1024 = 12288 edges vectorized
#define TAILB   (NVEC * 1024)            // 12288
#define TAILN   (EPC - TAILB)            // 212 scalar-tail edges
#define HWORDS  12500                    // u32 words per node-half (2 nodes/word)
#define QN      12500                    // wsum quarter width
#define G1_BM   ((NNODES + 127) / 128)   // 391
#define MEGA_NB (128 + 256 + 2 * G1_BM)  // 1166 (refillable schedule)
#define WS_NB   1536                     // spmm grid: 6 blocks/CU co-resident
#define NQUAD   (NNODES / 4)             // 12500

typedef __bf16 bf16x8 __attribute__((ext_vector_type(8)));
typedef float f32x4 __attribute__((ext_vector_type(4)));
typedef float f32x2 __attribute__((ext_vector_type(2)));

__device__ __forceinline__ unsigned short f2b(float f) {
    union { float f; unsigned u; } v; v.f = f;
    unsigned r = 0x7fffu + ((v.u >> 16) & 1u);
    return (unsigned short)((v.u + r) >> 16);
}
__device__ __forceinline__ unsigned char f2fp8(float x) {
    return (unsigned char)(__builtin_amdgcn_cvt_pk_fp8_f32(x, x, 0, false) & 0xff);
}
__device__ __forceinline__ float rdeg(int d) {      // rsqrt(max(d,1))
    return __frsqrt_rn((float)max(d, 1));
}

// ---------------- hist0: W1 cast + dst-hist (degIn) + src-hist (degOut) ----------------
__global__ __launch_bounds__(256) void k_hist0(
    const float* __restrict__ W1, unsigned short* __restrict__ W1t,
    const int* __restrict__ src, const int* __restrict__ dst,
    unsigned* __restrict__ degInP,   // [128][HWORDS]
    unsigned* __restrict__ degOutP)  // [128][HWORDS]
{
    __shared__ unsigned lds[HWORDS];   // 50 KB
    int bid = blockIdx.x, tid = threadIdx.x;

    if (bid < 256) {
        int id = bid * 256 + tid;      // 65536
        int k = id >> 8, n = id & 255;
        W1t[n * 256 + k] = f2b(W1[id]);
        return;
    }

    int b = bid - 256;                  // [0,256)
    const int* key = (b < 128) ? dst : src;
    unsigned* outP = (b < 128) ? degInP : degOutP;
    int b2 = b & 127;
    int c = b2 >> 1, h = b2 & 1;
    int lo = h * 25000;

    for (int i = tid; i < HWORDS; i += 256) lds[i] = 0;
    __syncthreads();
    int base = c * EPC;
    for (int i = 0; i < NVEC; i++) {
        int e = base + (i * 256 + tid) * 4;
        int4 k4 = *(const int4*)&key[e];
        int kk[4] = {k4.x, k4.y, k4.z, k4.w};
#pragma unroll
        for (int u = 0; u < 4; u++) {
            unsigned r = (unsigned)(kk[u] - lo);
            if (r < 25000u) atomicAdd(&lds[r >> 1], 1u << ((r & 1) * 16));
        }
    }
    if (tid < TAILN) {
        unsigned r = (unsigned)(key[base + TAILB + tid] - lo);
        if (r < 25000u) atomicAdd(&lds[r >> 1], 1u << ((r & 1) * 16));
    }
    __syncthreads();
    unsigned* op = outP + (size_t)b2 * HWORDS;
    for (int i = tid; i < HWORDS; i += 256) op[i] = lds[i];
}

// ---------------- merge0: prefix degInP -> chunkStart; degIn/degOut -> norms ----------------
__global__ __launch_bounds__(256) void k_merge0(
    const unsigned* __restrict__ degInP, const unsigned* __restrict__ degOutP,
    unsigned* __restrict__ chunkStartPk,   // [128][HWORDS]
    float* __restrict__ normIn, float* __restrict__ normOut,
    int* __restrict__ degc)
{
    int id = blockIdx.x * blockDim.x + threadIdx.x;
    if (id >= 25000) return;
    int h = id >= HWORDS, w = id - h * HWORDS;
    unsigned runLo = 0, runHi = 0, oLo = 0, oHi = 0;
#pragma unroll 8
    for (int c = 0; c < CH; c++) {
        size_t idx = (size_t)(c * 2 + h) * HWORDS + w;
        unsigned x = degInP[idx];
        chunkStartPk[idx] = runLo | (runHi << 16);
        runLo += x & 0xffffu; runHi += x >> 16;
        unsigned y = degOutP[idx];
        oLo += y & 0xffffu; oHi += y >> 16;
    }
    int d0 = h * 25000 + 2 * w, d1 = d0 + 1;
    normIn[d0] = rdeg((int)runLo);  normIn[d1] = rdeg((int)runHi);
    normOut[d0] = rdeg((int)oLo);   normOut[d1] = rdeg((int)oHi);
    degc[d0] = min((int)runLo, 64); degc[d1] = min((int)runHi, 64);
}

// ---------------- MEGA-2: edge-scatter + wsum-hist + GEMM1 (refillable, 0 dev atomics) ----------------
__global__ __launch_bounds__(256) void k_mega2(
    const int* __restrict__ src, const int* __restrict__ dst,
    const unsigned* __restrict__ chunkStartPk,
    unsigned short* __restrict__ col2,
    const float* __restrict__ normIn, const float* __restrict__ normOut,
    float* __restrict__ wsumP,
    const float* __restrict__ X, const unsigned short* __restrict__ W1t,
    unsigned char* __restrict__ H, int M)
{
    __shared__ __align__(16) unsigned char smem[50048];   // 50KB union
    int bid = blockIdx.x, tid = threadIdx.x;

    if (bid < 128) {
        // ---- counting-sort scatter (int4 edges) ----
        unsigned* cntL = (unsigned*)smem;
        int c = bid >> 1, h = bid & 1;
        int lo = h * 25000;
        const unsigned* cs = chunkStartPk + (size_t)(c * 2 + h) * HWORDS;
        for (int i = tid; i < HWORDS; i += 256) cntL[i] = cs[i];
        __syncthreads();
        int base = c * EPC;
        for (int i = 0; i < NVEC; i++) {
            int e = base + (i * 256 + tid) * 4;
            int4 d4 = *(const int4*)&dst[e];
            int4 s4 = *(const int4*)&src[e];
            int dd[4] = {d4.x, d4.y, d4.z, d4.w};
            int ss[4] = {s4.x, s4.y, s4.z, s4.w};
#pragma unroll
            for (int u = 0; u < 4; u++) {
                unsigned r = (unsigned)(dd[u] - lo);
                if (r < 25000u) {
                    unsigned sh = (r & 1) * 16;
                    unsigned wv = atomicAdd(&cntL[r >> 1], 1u << sh);
                    unsigned slot = (wv >> sh) & 0xffffu;
                    if (slot < 64) col2[(size_t)dd[u] * 64 + slot] = (unsigned short)ss[u];
                }
            }
        }
        if (tid < TAILN) {
            int e = base + TAILB + tid;
            int d = dst[e];
            unsigned r = (unsigned)(d - lo);
            if (r < 25000u) {
                int s = src[e];
                unsigned sh = (r & 1) * 16;
                unsigned wv = atomicAdd(&cntL[r >> 1], 1u << sh);
                unsigned slot = (wv >> sh) & 0xffffu;
                if (slot < 64) col2[(size_t)d * 64 + slot] = (unsigned short)s;
            }
        }
        return;
    }

    if (bid < 384) {
        // ---- wsum-hist role: gated normIn gather ----
        float* wf = (float*)smem;
        int b2 = bid - 128;            // [0,256)
        int c = b2 >> 2, q = b2 & 3;
        int lo = q * QN;
        for (int i = tid; i < QN; i += 256) wf[i] = 0.f;
        __syncthreads();
        int base = c * EPC;
        for (int i = 0; i < NVEC; i++) {
            int e = base + (i * 256 + tid) * 4;
            int4 s4 = *(const int4*)&src[e];
            int4 d4 = *(const int4*)&dst[e];
            int ss[4] = {s4.x, s4.y, s4.z, s4.w};
            int dd[4] = {d4.x, d4.y, d4.z, d4.w};
#pragma unroll
            for (int u = 0; u < 4; u++) {
                unsigned r = (unsigned)(ss[u] - lo);
                if (r < (unsigned)QN) {
                    float ni = normIn[dd[u]];
                    atomicAdd(&wf[r], ni);
                }
            }
        }
        if (tid < TAILN) {
            int e = base + TAILB + tid;
            unsigned r = (unsigned)(src[e] - lo);
            if (r < (unsigned)QN) atomicAdd(&wf[r], normIn[dst[e]]);
        }
        __syncthreads();
        float* op = wsumP + (size_t)b2 * QN;
        for (int i = tid; i < QN; i += 256) op[i] = wf[i];
        return;
    }

    // ---- GEMM1 role: one 128x128 tile per block, H = fp8(normOut*(X@W1)) ----
    unsigned short (*As)[40] = (unsigned short (*)[40])smem;
    unsigned short (*Bs)[40] = (unsigned short (*)[40])(smem + 10240);
    int g = bid - 384;                  // [0, 782)
    int bm = g % G1_BM, bn = g / G1_BM;
    int m0 = bm * 128, n0 = bn * 128;
    int lane = tid & 63, wave = tid >> 6;
    int wm = (wave >> 1) * 64, wn = (wave & 1) * 64;
    int q = lane >> 4, r16 = lane & 15;

    f32x4 acc[4][4];
#pragma unroll
    for (int i = 0; i < 4; i++)
#pragma unroll
        for (int j = 0; j < 4; j++) acc[i][j] = 0.f;

    int c0 = tid, c1 = tid + 256;
    int r0 = c0 >> 2, k0c = (c0 & 3) * 8;
    int r1 = c1 >> 2, k1c = (c1 & 3) * 8;
    const float* Ar0 = X + (size_t)min(m0 + r0, M - 1) * 256;
    const float* Ar1 = X + (size_t)min(m0 + r1, M - 1) * 256;
    const unsigned short* Br0 = W1t + (size_t)(n0 + r0) * 256;
    const unsigned short* Br1 = W1t + (size_t)(n0 + r1) * 256;

    auto pk2u = [](float a, float b) -> unsigned {
        unsigned short x = f2b(a), y = f2b(b);
        return (unsigned)x | ((unsigned)y << 16);
    };

    for (int k0 = 0; k0 < 256; k0 += 32) {
        float4 fa0 = *(const float4*)(Ar0 + k0 + k0c);
        float4 fa1 = *(const float4*)(Ar0 + k0 + k0c + 4);
        float4 fb0 = *(const float4*)(Ar1 + k0 + k1c);
        float4 fb1 = *(const float4*)(Ar1 + k0 + k1c + 4);
        uint4 vb0 = *(const uint4*)(Br0 + k0 + k0c);
        uint4 vb1 = *(const uint4*)(Br1 + k0 + k1c);
        uint4 va0 = make_uint4(pk2u(fa0.x, fa0.y), pk2u(fa0.z, fa0.w), pk2u(fa1.x, fa1.y), pk2u(fa1.z, fa1.w));
        uint4 va1 = make_uint4(pk2u(fb0.x, fb0.y), pk2u(fb0.z, fb0.w), pk2u(fb1.x, fb1.y), pk2u(fb1.z, fb1.w));
        __syncthreads();
        *(uint4*)&As[r0][k0c] = va0;
        *(uint4*)&As[r1][k1c] = va1;
        *(uint4*)&Bs[r0][k0c] = vb0;
        *(uint4*)&Bs[r1][k1c] = vb1;
        __syncthreads();
        bf16x8 af[4], bf[4];
#pragma unroll
        for (int i = 0; i < 4; i++)
            af[i] = *(const bf16x8*)&As[wm + i * 16 + r16][q * 8];
#pragma unroll
        for (int j = 0; j < 4; j++)
            bf[j] = *(const bf16x8*)&Bs[wn + j * 16 + r16][q * 8];
#pragma unroll
        for (int i = 0; i < 4; i++)
#pragma unroll
            for (int j = 0; j < 4; j++)
                acc[i][j] = __builtin_amdgcn_mfma_f32_16x16x32_bf16(af[i], bf[j], acc[i][j], 0, 0, 0);
    }

#pragma unroll
    for (int i = 0; i < 4; i++) {
#pragma unroll
        for (int rr = 0; rr < 4; rr++) {
            int m = m0 + wm + i * 16 + q * 4 + rr;
            if (m < M) {
                float no = normOut[m];
                unsigned char* Hp = H + (size_t)m * 256 + n0 + wn + r16;
#pragma unroll
                for (int j = 0; j < 4; j++)
                    Hp[j * 16] = f2fp8(acc[i][j][rr] * no);
            }
        }
    }
}

// ---------------- merge1: wsum partials -> meta = {wgt, normIn, degc, 0} ----------------
__global__ __launch_bounds__(256) void k_merge1(
    const float* __restrict__ wsumP, const float* __restrict__ normOut,
    const float* __restrict__ normIn, const int* __restrict__ degc,
    float4* __restrict__ meta)
{
    int i = blockIdx.x * blockDim.x + threadIdx.x;
    if (i >= NNODES) return;
    int q = i / QN, li = i - q * QN;
    float ws = 0.f;
#pragma unroll 8
    for (int c = 0; c < CH; c++) ws += wsumP[(size_t)(c * 4 + q) * QN + li];
    meta[i] = make_float4(normOut[i] * ws, normIn[i],
                          __int_as_float(degc[i]), 0.f);
}

// ---------------- SpMM layer1 + weighted feature-sum (R9 exact structure) ----------------
// One wave per node. col2 row loaded once per node, indices via v_readlane,
// UNCONDITIONAL 16-wide gather batches (keeps 16 loads in flight).
__global__ __launch_bounds__(256) void k_spmm_wsum(
    const unsigned char* __restrict__ H, const float4* __restrict__ meta,
    const unsigned short* __restrict__ col2,
    const float* __restrict__ bias, float* __restrict__ vpart) {
    __shared__ float sm[4][256];
    int wave = threadIdx.x >> 6;
    int lane = threadIdx.x & 63;
    int f = lane * 4;
    const unsigned char* Hf = H + f;
    float4 bv = *(const float4*)(bias + f);
    float vac0 = 0.f, vac1 = 0.f, vac2 = 0.f, vac3 = 0.f;

    int qd = blockIdx.x;
    int node = qd * 4 + wave;
    float4 pM = make_float4(0.f, 0.f, 0.f, 0.f);
    int pc = 0;
    if (qd < NQUAD) {
        pM = meta[node];
        pc = (int)col2[(size_t)node * 64 + lane];
    }

    while (qd < NQUAD) {
        float wn = pM.x, nI = pM.y;
        int dI = __float_as_int(pM.z), myc = pc;

        int nqd = qd + gridDim.x;
        if (nqd < NQUAD) {
            int nn = nqd * 4 + wave;
            pM = meta[nn];
            pc = (int)col2[(size_t)nn * 64 + lane];
        }

        float a0 = 0.f, a1 = 0.f, a2 = 0.f, a3 = 0.f;
        int i = 0;
        for (; i + 16 <= dI; i += 16) {
            unsigned v[16];
#pragma unroll
            for (int u = 0; u < 16; u++) {
                int c = __builtin_amdgcn_readlane(myc, i + u);
                v[u] = *(const unsigned*)(Hf + (size_t)c * 256);
            }
#pragma unroll
            for (int u = 0; u < 16; u++) {
                f32x2 lo = __builtin_amdgcn_cvt_pk_f32_fp8(v[u], false);
                f32x2 hi = __builtin_amdgcn_cvt_pk_f32_fp8(v[u], true);
                a0 += lo.x; a1 += lo.y; a2 += hi.x; a3 += hi.y;
            }
        }
        for (; i + 4 <= dI; i += 4) {
            unsigned v[4];
#pragma unroll
            for (int u = 0; u < 4; u++) {
                int c = __builtin_amdgcn_readlane(myc, i + u);
                v[u] = *(const unsigned*)(Hf + (size_t)c * 256);
            }
#pragma unroll
            for (int u = 0; u < 4; u++) {
                f32x2 lo = __builtin_amdgcn_cvt_pk_f32_fp8(v[u], false);
                f32x2 hi = __builtin_amdgcn_cvt_pk_f32_fp8(v[u], true);
                a0 += lo.x; a1 += lo.y; a2 += hi.x; a3 += hi.y;
            }
        }
        for (; i < dI; i++) {
            int c = __builtin_amdgcn_readlane(myc, i);
            unsigned v = *(const unsigned*)(Hf + (size_t)c * 256);
            f32x2 lo = __builtin_amdgcn_cvt_pk_f32_fp8(v, false);
            f32x2 hi = __builtin_amdgcn_cvt_pk_f32_fp8(v, true);
            a0 += lo.x; a1 += lo.y; a2 += hi.x; a3 += hi.y;
        }

        vac0 += wn * fmaxf(a0 * nI + bv.x, 0.f);
        vac1 += wn * fmaxf(a1 * nI + bv.y, 0.f);
        vac2 += wn * fmaxf(a2 * nI + bv.z, 0.f);
        vac3 += wn * fmaxf(a3 * nI + bv.w, 0.f);

        qd = nqd;
    }

    *(float4*)&sm[wave][f] = make_float4(vac0, vac1, vac2, vac3);
    __syncthreads();
    int t = threadIdx.x;
    float s4 = sm[0][t] + sm[1][t] + sm[2][t] + sm[3][t];
    vpart[(size_t)blockIdx.x * 256 + t] = s4;
}

// ---------------- tree reduce stage: WS_NB rows -> 64 rows ----------------
__global__ __launch_bounds__(256) void k_red1(const float* __restrict__ vpart,
                                              float* __restrict__ vred) {
    int b = blockIdx.x;
    int t = threadIdx.x;
    float s = 0.f;
    for (int i = b; i < WS_NB; i += 64) s += vpart[(size_t)i * 256 + t];
    vred[(size_t)b * 256 + t] = s;
}

// ---------------- final: v = sum(vred); out = v@W2/N + b2 ----------------
__global__ __launch_bounds__(1024) void k_final(
    const float* __restrict__ vred, const float* __restrict__ W2,
    const float* __restrict__ b2, float* __restrict__ out) {
    __shared__ float part[4][256];
    __shared__ float v[256];
    int t = threadIdx.x;
    int feat = t & 255, pr = t >> 8;
    float s = 0.f;
    for (int i = pr; i < 64; i += 4) s += vred[(size_t)i * 256 + feat];
    part[pr][feat] = s;
    __syncthreads();
    if (t < 256) v[t] = part[0][t] + part[1][t] + part[2][t] + part[3][t];
    __syncthreads();
    if (t < 128) {
        float o = 0.f;
        for (int k = 0; k < 256; k++) o += v[k] * W2[k * 128 + t];
        out[t] = o * (1.0f / (float)NNODES) + b2[t];
    }
}

extern "C" void kernel_launch(void* const* d_in, const int* in_sizes, int n_in,
                              void* d_out, int out_size, void* d_ws, size_t ws_size,
                              hipStream_t stream) {
    const float* X   = (const float*)d_in[0];
    const int*   src = (const int*)d_in[1];
    const int*   dst = (const int*)d_in[2];
    const float* W1  = (const float*)d_in[3];
    const float* b1  = (const float*)d_in[4];
    const float* W2  = (const float*)d_in[5];
    const float* b2  = (const float*)d_in[6];
    float* out = (float*)d_out;

    const int n = NNODES;

    char* p = (char*)d_ws;
    auto carve = [&](size_t bytes) -> void* {
        void* r = (void*)p;
        p += (bytes + 255) & ~(size_t)255;
        return r;
    };
    unsigned short* col2 = (unsigned short*)carve((size_t)n * 64 * 2);      // 6.4 MB
    unsigned short* W1t  = (unsigned short*)carve((size_t)256 * 256 * 2);
    unsigned char*  bufA = (unsigned char*)carve((size_t)n * 256);          // 12.8 MB fp8 H'
    float* normIn  = (float*)carve((size_t)n * sizeof(float));
    float* normOut = (float*)carve((size_t)n * sizeof(float));
    int*   degc    = (int*)carve((size_t)n * sizeof(int));
    float4* meta   = (float4*)carve((size_t)n * sizeof(float4));            // 800 KB
    // degInP/degOutP dead after merge0 -> region reused by wsumP (born in mega2)
    size_t histP_bytes = (size_t)128 * HWORDS * sizeof(unsigned);           // 6.4 MB each
    char* histr = (char*)carve(2 * histP_bytes);                            // 12.8 MB
    unsigned* degInP  = (unsigned*)histr;
    unsigned* degOutP = (unsigned*)(histr + histP_bytes);
    float*    wsumP   = (float*)histr;                                      // [256][QN] alias
    // chunkStartPk dead after mega2 -> region reused by vpart/vred
    char* csr = (char*)carve(histP_bytes);                                  // 6.4 MB
    unsigned* chunkStartPk = (unsigned*)csr;
    float* vpart = (float*)csr;                                             // 1.5 MB alias
    float* vred  = (float*)(csr + (size_t)WS_NB * 256 * sizeof(float));

    // ---- hist0: W1 cast + dst/src LDS histograms ----
    k_hist0<<<512, 256, 0, stream>>>(W1, W1t, src, dst, degInP, degOutP);

    // ---- merge0: prefix -> chunkStart, norms, degc ----
    k_merge0<<<98, 256, 0, stream>>>(degInP, degOutP, chunkStartPk,
                                     normIn, normOut, degc);

    // ---- MEGA-2: scatter || wsum (gated) || GEMM1 -- refillable grid ----
    k_mega2<<<MEGA_NB, 256, 0, stream>>>(
        src, dst, chunkStartPk, col2, normIn, normOut, wsumP, X, W1t, bufA, n);

    // ---- merge1: meta = {wgt, normIn, degc} ----
    k_merge1<<<(n + 255) / 256, 256, 0, stream>>>(wsumP, normOut, normIn, degc, meta);

    // ---- layer-1 gather + weighted feature-sum ----
    k_spmm_wsum<<<WS_NB, 256, 0, stream>>>(bufA, meta, col2, b1, vpart);

    // ---- tree reduce + final matvec ----
    k_red1<<<64, 256, 0, stream>>>(vpart, vred);
    k_final<<<1, 1024, 0, stream>>>(vred, W2, b2, out);
}